// Round 6
// baseline (150.928 us; speedup 1.0000x reference)
//
#include <hip/hip_runtime.h>

// x [B=64, C=512, H=28, W=28] f32, cc [B,H,W] bool.
// out[b, 0:512]    = (sum_hw x*m + x[b,c,0,0]) / (cnt==0 ? 1 : cnt)
// out[b, 512:1024] = max_hw x
//
// Single fused barrier-free kernel. Each wave owns 16 channels of one batch:
// mask row held in registers, cc encoding self-detected (int32/f32/uint8)
// via in-bounds sample + wave votes, x streamed with nontemporal float4
// loads (read-once; keep L2 for the reused mask rows), mask count folded
// into the shuffle reduction. 512 blocks = 2 blocks/CU, uniform work.

#define HW 784      // 28*28
#define NC 512
#define NB 64
#define CPW 16      // channels per wave

typedef float  vfloat4 __attribute__((ext_vector_type(4)));

__device__ __forceinline__ float dot4(float4 a, float4 b) {
    return a.x * b.x + a.y * b.y + a.z * b.z + a.w * b.w;
}
__device__ __forceinline__ float max4(float4 a) {
    return fmaxf(fmaxf(a.x, a.y), fmaxf(a.z, a.w));
}
__device__ __forceinline__ float sum4(float4 a) {
    return a.x + a.y + a.z + a.w;
}
__device__ __forceinline__ float4 unpack_u8(unsigned int u) {
    return make_float4((float)(u & 0xff), (float)((u >> 8) & 0xff),
                       (float)((u >> 16) & 0xff), (float)((u >> 24) & 0xff));
}
__device__ __forceinline__ float4 ntload4(const float4* p) {
    vfloat4 v = __builtin_nontemporal_load((const vfloat4*)p);
    return make_float4(v.x, v.y, v.z, v.w);
}

__global__ __launch_bounds__(256) void pool_fused_kernel(
    const float* __restrict__ x, const void* __restrict__ cc,
    float* __restrict__ out)
{
    const int blk  = blockIdx.x;      // 512 blocks
    const int b    = blk >> 3;
    const int grp  = blk & 7;
    const int t    = threadIdx.x;
    const int wave = t >> 6;
    const int lane = t & 63;
    const int c0   = grp * (4 * CPW) + wave * CPW;

    // ---- encoding detection (wave-local, no barrier) ----
    // Sample 196 ints at byte offset b*784: in-bounds for uint8 (50176 B)
    // and int32/f32 (200704 B) encodings alike.
    int badInt = 0, badFlt = 0;
    {
        const int4* det = (const int4*)((const unsigned char*)cc + (size_t)b * HW);
        if (lane < 49) {
            int4 d = det[lane];
            badInt = (d.x | d.y | d.z | d.w) & ~1;
            badFlt = (d.x && d.x != 0x3F800000) || (d.y && d.y != 0x3F800000) ||
                     (d.z && d.z != 0x3F800000) || (d.w && d.w != 0x3F800000);
        }
    }
    const bool isInt = !__any(badInt != 0);
    const bool isFlt = !__any(badFlt);

    // ---- mask row -> registers (lane covers float4s lane, +64, +128, +192<4) ----
    float4 m0, m1, m2, m3 = make_float4(0.f, 0.f, 0.f, 0.f);
    if (isInt) {
        const int4* mi = (const int4*)cc + (size_t)b * 196;
        int4 a = mi[lane], e = mi[lane + 64], f = mi[lane + 128];
        m0 = make_float4((float)a.x, (float)a.y, (float)a.z, (float)a.w);
        m1 = make_float4((float)e.x, (float)e.y, (float)e.z, (float)e.w);
        m2 = make_float4((float)f.x, (float)f.y, (float)f.z, (float)f.w);
        if (lane < 4) {
            int4 g = mi[lane + 192];
            m3 = make_float4((float)g.x, (float)g.y, (float)g.z, (float)g.w);
        }
    } else if (isFlt) {
        const float4* mf = (const float4*)cc + (size_t)b * 196;
        m0 = mf[lane]; m1 = mf[lane + 64]; m2 = mf[lane + 128];
        if (lane < 4) m3 = mf[lane + 192];
    } else {
        const unsigned int* row =
            (const unsigned int*)((const unsigned char*)cc + (size_t)b * HW);
        m0 = unpack_u8(row[lane]);
        m1 = unpack_u8(row[lane + 64]);
        m2 = unpack_u8(row[lane + 128]);
        if (lane < 4) m3 = unpack_u8(row[lane + 192]);
    }

    float mc = sum4(m0) + sum4(m1) + sum4(m2) + sum4(m3);  // partial mask count

    // ---- CPW channels per wave: coalesced nontemporal float4 stream of x ----
    float s[CPW], mx[CPW];
#pragma unroll
    for (int j = 0; j < CPW; ++j) {
        const float4* xr = (const float4*)(x + (size_t)(b * NC + c0 + j) * HW);
        float4 q0 = ntload4(xr + lane);
        float4 q1 = ntload4(xr + lane + 64);
        float4 q2 = ntload4(xr + lane + 128);
        float sum = dot4(q0, m0) + dot4(q1, m1) + dot4(q2, m2);
        float mm  = fmaxf(fmaxf(max4(q0), max4(q1)), max4(q2));
        if (lane < 4) {
            float4 q3 = ntload4(xr + lane + 192);
            sum += dot4(q3, m3);
            mm = fmaxf(mm, max4(q3));
        }
        if (lane == 0) sum += q0.x;   // reference's + x[b,c,0,0] term
        s[j] = sum; mx[j] = mm;
    }

    // ---- wave reductions: CPW sums, CPW maxes, 1 count ----
    for (int off = 32; off > 0; off >>= 1) {
        mc += __shfl_down(mc, off);
#pragma unroll
        for (int j = 0; j < CPW; ++j) {
            s[j] += __shfl_down(s[j], off);
            mx[j] = fmaxf(mx[j], __shfl_down(mx[j], off));
        }
    }

    if (lane == 0) {
        const float inv = 1.0f / ((mc == 0.0f) ? 1.0f : mc);
#pragma unroll
        for (int j = 0; j < CPW; ++j) {
            const int c = c0 + j;
            out[(size_t)b * (2 * NC) + c]      = s[j] * inv;
            out[(size_t)b * (2 * NC) + NC + c] = mx[j];
        }
    }
}

extern "C" void kernel_launch(void* const* d_in, const int* in_sizes, int n_in,
                              void* d_out, int out_size, void* d_ws, size_t ws_size,
                              hipStream_t stream) {
    const float* x  = (const float*)d_in[0];
    const void*  cc = d_in[1];
    float* out = (float*)d_out;
    pool_fused_kernel<<<dim3(NB * 8), dim3(256), 0, stream>>>(x, cc, out);
}

// Round 7
// 145.375 us; speedup vs baseline: 1.0382x; 1.0382x over previous
//
#include <hip/hip_runtime.h>

// x [B=64, C=512, H=28, W=28] f32, cc [B,H,W] bool.
// out[b, 0:512]    = (sum_hw x*m + x[b,c,0,0]) / (cnt==0 ? 1 : cnt)
// out[b, 512:1024] = max_hw x
//
// Single fused barrier-free kernel. Each wave owns 8 channels of one batch:
// holds the 784-elem mask row in registers, self-detects cc encoding
// (int32 / f32 / uint8) via in-bounds sample + wave votes, streams x with
// nontemporal float4 loads (read-once; don't thrash L2), folds the mask
// count into the shuffle reduction. 1024 blocks = 4 blocks/CU, uniform work.
//
// Tuning history: 4 ch/wave = 152 us, 8 ch/wave = 143.5 us, 16 ch/wave =
// 150.9 us (occupancy drop to 2 blocks/CU starves HBM latency hiding).
// 8 ch/wave at 16 waves/CU is the bracketed optimum.

#define HW 784      // 28*28
#define NC 512
#define NB 64

typedef float  vfloat4 __attribute__((ext_vector_type(4)));

__device__ __forceinline__ float dot4(float4 a, float4 b) {
    return a.x * b.x + a.y * b.y + a.z * b.z + a.w * b.w;
}
__device__ __forceinline__ float max4(float4 a) {
    return fmaxf(fmaxf(a.x, a.y), fmaxf(a.z, a.w));
}
__device__ __forceinline__ float sum4(float4 a) {
    return a.x + a.y + a.z + a.w;
}
__device__ __forceinline__ float4 unpack_u8(unsigned int u) {
    return make_float4((float)(u & 0xff), (float)((u >> 8) & 0xff),
                       (float)((u >> 16) & 0xff), (float)((u >> 24) & 0xff));
}
__device__ __forceinline__ float4 ntload4(const float4* p) {
    vfloat4 v = __builtin_nontemporal_load((const vfloat4*)p);
    return make_float4(v.x, v.y, v.z, v.w);
}

__global__ __launch_bounds__(256) void pool_fused_kernel(
    const float* __restrict__ x, const void* __restrict__ cc,
    float* __restrict__ out)
{
    const int blk  = blockIdx.x;      // 1024 blocks
    const int b    = blk >> 4;
    const int grp  = blk & 15;
    const int t    = threadIdx.x;
    const int wave = t >> 6;
    const int lane = t & 63;
    const int c0   = grp * 32 + wave * 8;   // 8 channels per wave

    // ---- encoding detection (wave-local, no barrier) ----
    // Sample 196 ints at byte offset b*784: in-bounds for uint8 (50176 B)
    // and int32/f32 (200704 B) encodings alike.
    int badInt = 0, badFlt = 0;
    {
        const int4* det = (const int4*)((const unsigned char*)cc + (size_t)b * HW);
        if (lane < 49) {
            int4 d = det[lane];
            badInt = (d.x | d.y | d.z | d.w) & ~1;
            badFlt = (d.x && d.x != 0x3F800000) || (d.y && d.y != 0x3F800000) ||
                     (d.z && d.z != 0x3F800000) || (d.w && d.w != 0x3F800000);
        }
    }
    const bool isInt = !__any(badInt != 0);
    const bool isFlt = !__any(badFlt);

    // ---- mask row -> registers (lane covers float4s lane, +64, +128, +192<4) ----
    float4 m0, m1, m2, m3 = make_float4(0.f, 0.f, 0.f, 0.f);
    if (isInt) {
        const int4* mi = (const int4*)cc + (size_t)b * 196;
        int4 a = mi[lane], e = mi[lane + 64], f = mi[lane + 128];
        m0 = make_float4((float)a.x, (float)a.y, (float)a.z, (float)a.w);
        m1 = make_float4((float)e.x, (float)e.y, (float)e.z, (float)e.w);
        m2 = make_float4((float)f.x, (float)f.y, (float)f.z, (float)f.w);
        if (lane < 4) {
            int4 g = mi[lane + 192];
            m3 = make_float4((float)g.x, (float)g.y, (float)g.z, (float)g.w);
        }
    } else if (isFlt) {
        const float4* mf = (const float4*)cc + (size_t)b * 196;
        m0 = mf[lane]; m1 = mf[lane + 64]; m2 = mf[lane + 128];
        if (lane < 4) m3 = mf[lane + 192];
    } else {
        const unsigned int* row =
            (const unsigned int*)((const unsigned char*)cc + (size_t)b * HW);
        m0 = unpack_u8(row[lane]);
        m1 = unpack_u8(row[lane + 64]);
        m2 = unpack_u8(row[lane + 128]);
        if (lane < 4) m3 = unpack_u8(row[lane + 192]);
    }

    float mc = sum4(m0) + sum4(m1) + sum4(m2) + sum4(m3);  // partial mask count

    // ---- 8 channels per wave: coalesced nontemporal float4 stream of x ----
    float s[8], mx[8];
#pragma unroll
    for (int j = 0; j < 8; ++j) {
        const float4* xr = (const float4*)(x + (size_t)(b * NC + c0 + j) * HW);
        float4 q0 = ntload4(xr + lane);
        float4 q1 = ntload4(xr + lane + 64);
        float4 q2 = ntload4(xr + lane + 128);
        float sum = dot4(q0, m0) + dot4(q1, m1) + dot4(q2, m2);
        float mm  = fmaxf(fmaxf(max4(q0), max4(q1)), max4(q2));
        if (lane < 4) {
            float4 q3 = ntload4(xr + lane + 192);
            sum += dot4(q3, m3);
            mm = fmaxf(mm, max4(q3));
        }
        if (lane == 0) sum += q0.x;   // reference's + x[b,c,0,0] term
        s[j] = sum; mx[j] = mm;
    }

    // ---- wave reductions: 8 sums, 8 maxes, 1 count ----
    for (int off = 32; off > 0; off >>= 1) {
        mc += __shfl_down(mc, off);
#pragma unroll
        for (int j = 0; j < 8; ++j) {
            s[j] += __shfl_down(s[j], off);
            mx[j] = fmaxf(mx[j], __shfl_down(mx[j], off));
        }
    }

    if (lane == 0) {
        const float inv = 1.0f / ((mc == 0.0f) ? 1.0f : mc);
#pragma unroll
        for (int j = 0; j < 8; ++j) {
            const int c = c0 + j;
            out[(size_t)b * (2 * NC) + c]      = s[j] * inv;
            out[(size_t)b * (2 * NC) + NC + c] = mx[j];
        }
    }
}

extern "C" void kernel_launch(void* const* d_in, const int* in_sizes, int n_in,
                              void* d_out, int out_size, void* d_ws, size_t ws_size,
                              hipStream_t stream) {
    const float* x  = (const float*)d_in[0];
    const void*  cc = d_in[1];
    float* out = (float*)d_out;
    pool_fused_kernel<<<dim3(NB * 16), dim3(256), 0, stream>>>(x, cc, out);
}